// Round 10
// baseline (140.061 us; speedup 1.0000x reference)
//
#include <hip/hip_runtime.h>
#include <hip/hip_bf16.h>
#include <hip/hip_cooperative_groups.h>

namespace cg = cooperative_groups;

typedef __bf16 bf16x8 __attribute__((ext_vector_type(8)));
typedef float f32x4 __attribute__((ext_vector_type(4)));
typedef unsigned short ushort8 __attribute__((ext_vector_type(8)));
typedef unsigned short ushort4v __attribute__((ext_vector_type(4)));

constexpr int M = 128;             // B*T
constexpr int K = 4096;            // IN
constexpr int N = 11008;           // OUT
constexpr int BN = 128;            // N cols per block
constexpr int BK = 32;             // K per step
constexpr int KSPLIT = 4;
constexpr int KBLK = K / KSPLIT;   // 1024
constexpr int NBX = N / BN;        // 86
constexpr int GRID = NBX * KSPLIT; // 344
constexpr long long NW = (long long)N * K;
constexpr size_t MN = (size_t)M * N;

// ws layout
constexpr size_t PART_OFF = 0;                              // 344 f32 partials
constexpr size_t P_OFF = 8192;                              // 4 partial outputs
constexpr size_t WS_NEED_SPLIT = P_OFF + KSPLIT * MN * sizeof(float);
constexpr size_t WS_NEED_MIN = GRID * sizeof(float);

__device__ __forceinline__ unsigned short f2bf_bits(float f) {
    unsigned int u = __builtin_bit_cast(unsigned int, f);
    u += 0x7FFFu + ((u >> 16) & 1u);            // RNE to bf16
    return (unsigned short)(u >> 16);
}

// ---- standalone per-tile |W| reduce (non-coop fallback), grid (86,4) ----
__global__ __launch_bounds__(256) void absmean_tiles(const float* __restrict__ W,
                                                     float* __restrict__ partials)
{
    const int tid = threadIdx.x;
    const int n0 = blockIdx.x * BN, kk0 = blockIdx.y * KBLK;
    const float4* w4p = (const float4*)W;
    const int K4 = K / 4;
    float s0 = 0.f, s1 = 0.f, s2 = 0.f, s3 = 0.f;
    for (int r = 0; r < BN; ++r) {
        float4 v = w4p[(size_t)(n0 + r) * K4 + kk0 / 4 + tid];
        s0 += fabsf(v.x); s1 += fabsf(v.y); s2 += fabsf(v.z); s3 += fabsf(v.w);
    }
    float s = (s0 + s1) + (s2 + s3);
#pragma unroll
    for (int off = 32; off > 0; off >>= 1) s += __shfl_down(s, off, 64);
    __shared__ float red[4];
    if ((tid & 63) == 0) red[tid >> 6] = s;
    __syncthreads();
    if (tid == 0)
        partials[blockIdx.y * NBX + blockIdx.x] = (red[0] + red[1]) + (red[2] + red[3]);
}

// ---- fused: [phase A reduce + grid.sync (COOP)] + quantize + GEMM ----
// COOP,!DIRECT: cooperative grid (86,4); W re-read is L3-hot from phase A
// !COOP,!DIRECT: grid (86,4), partials precomputed by absmean_tiles
// !COOP, DIRECT: grid (86,1), full K, writes out+bias (tiny-ws fallback)
template <bool COOP, bool DIRECT>
__global__ __launch_bounds__(256, 2) void bitlinear_fused(
    const float* __restrict__ X, const float* __restrict__ W,
    const float* __restrict__ bias, float* __restrict__ partials,
    float* __restrict__ dbase)
{
    constexpr int KSTEPS = DIRECT ? K / BK : KBLK / BK;
    constexpr int LDSW = 40;                    // 32 + 8 pad shorts (80 B rows)
    __shared__ __attribute__((aligned(16))) unsigned short xs[2][M * LDSW];
    __shared__ __attribute__((aligned(16))) unsigned short wsm[2][BN * LDSW];
    __shared__ float red[4];

    const int tid = threadIdx.x;
    const int lane = tid & 63;
    const int wid = tid >> 6;
    const int wm = wid >> 1;                    // 0..1: M 64-half
    const int wn = wid & 1;                     // 0..1: N 64-half
    const int cgrp = lane >> 4;                 // 0..3
    const int l15 = lane & 15;
    const int n0 = blockIdx.x * BN;
    const int by = DIRECT ? 0 : blockIdx.y;
    const int kk0 = DIRECT ? 0 : by * KBLK;
    const int K4 = K / 4;
    const float4* w4p = (const float4*)W;
    const float4* x4p = (const float4*)X;

    if constexpr (COOP) {
        // phase A: |W| over this block's own GEMM tile [n0,n0+128) x [kk0,kk0+1024)
        float s0 = 0.f, s1 = 0.f, s2 = 0.f, s3 = 0.f;
        for (int r = 0; r < BN; ++r) {
            float4 v = w4p[(size_t)(n0 + r) * K4 + kk0 / 4 + tid];
            s0 += fabsf(v.x); s1 += fabsf(v.y); s2 += fabsf(v.z); s3 += fabsf(v.w);
        }
        float s = (s0 + s1) + (s2 + s3);
#pragma unroll
        for (int off = 32; off > 0; off >>= 1) s += __shfl_down(s, off, 64);
        if (lane == 0) red[wid] = s;
        __syncthreads();
        if (tid == 0)
            partials[by * NBX + blockIdx.x] = (red[0] + red[1]) + (red[2] + red[3]);
        cg::this_grid().sync();                 // all partials written + visible
    }

    // staging regs
    ushort8 xr[2];
    float4 wrf[4];

    auto issue = [&](int t) {
#pragma unroll
        for (int i = 0; i < 2; ++i) {           // X: 512 slots, row=j>>2, ch=j&3
            const int j = tid + i * 256;
            const int row = j >> 2, ch = j & 3;
            const float4* xp = x4p + (size_t)row * K4 + (kk0 + t * BK) / 4 + ch * 2;
            float4 a = xp[0], b = xp[1];
            ushort8 o;
            o[0] = f2bf_bits(a.x); o[1] = f2bf_bits(a.y);
            o[2] = f2bf_bits(a.z); o[3] = f2bf_bits(a.w);
            o[4] = f2bf_bits(b.x); o[5] = f2bf_bits(b.y);
            o[6] = f2bf_bits(b.z); o[7] = f2bf_bits(b.w);
            xr[i] = o;
        }
#pragma unroll
        for (int i = 0; i < 4; ++i) {           // W: 1024 slots, row=j>>3, q=j&7
            const int j = tid + i * 256;
            const int row = j >> 3, q = j & 7;
            wrf[i] = w4p[(size_t)(n0 + row) * K4 + (kk0 + t * BK) / 4 + q];
        }
    };

    // tile-0 loads in flight over the delta reduce
    issue(0);

    float delta;
    {
        float s = 0.f;
        for (int i = tid; i < GRID; i += 256) s += partials[i];
#pragma unroll
        for (int off = 32; off > 0; off >>= 1) s += __shfl_down(s, off, 64);
        if (lane == 0) red[wid] = s;
        __syncthreads();
        delta = (float)((double)((red[0] + red[1]) + (red[2] + red[3])) /
                        (double)NW + 1e-8);
    }
    const float inv_delta = 1.0f / delta;

    auto stage = [&](int buf) {
#pragma unroll
        for (int i = 0; i < 2; ++i) {
            const int j = tid + i * 256;
            *(ushort8*)&xs[buf][(j >> 2) * LDSW + (j & 3) * 8] = xr[i];
        }
#pragma unroll
        for (int i = 0; i < 4; ++i) {
            const int j = tid + i * 256;
            const int row = j >> 3, q = j & 7;
            float wf[4] = {wrf[i].x, wrf[i].y, wrf[i].z, wrf[i].w};
            ushort4v wq;
#pragma unroll
            for (int e = 0; e < 4; ++e) {
                float qv = rintf(wf[e] * inv_delta);   // RNE = jnp.round, exact f32
                qv = fminf(1.f, fmaxf(-1.f, qv));
                wq[e] = f2bf_bits(qv);                 // exact bf16 {-1,0,+1}
            }
            *(ushort4v*)&wsm[buf][row * LDSW + q * 4] = wq;
        }
    };

    stage(0);
    __syncthreads();

    f32x4 acc[4][4] = {};

    for (int t = 0; t < KSTEPS; ++t) {
        const int cur = t & 1;
        if (t + 1 < KSTEPS) issue(t + 1);       // globals in flight over MFMA
        const unsigned short* xcur = xs[cur];
        const unsigned short* wcur = wsm[cur];
        bf16x8 afr[4], bfr[4];
#pragma unroll
        for (int f = 0; f < 4; ++f)
            afr[f] = *(const bf16x8*)&xcur[(wm * 64 + f * 16 + l15) * LDSW + cgrp * 8];
#pragma unroll
        for (int g = 0; g < 4; ++g)
            bfr[g] = *(const bf16x8*)&wcur[(wn * 64 + g * 16 + l15) * LDSW + cgrp * 8];
#pragma unroll
        for (int f = 0; f < 4; ++f)
#pragma unroll
            for (int g = 0; g < 4; ++g)
                acc[f][g] = __builtin_amdgcn_mfma_f32_16x16x32_bf16(
                    afr[f], bfr[g], acc[f][g], 0, 0, 0);
        if (t + 1 < KSTEPS) stage(cur ^ 1);
        __syncthreads();
    }

    // epilogue: D col=lane&15, row=(lane>>4)*4+reg (validated)
    float* dst = DIRECT ? dbase : dbase + (size_t)by * MN;
#pragma unroll
    for (int f = 0; f < 4; ++f) {
        const int mrow = wm * 64 + f * 16 + cgrp * 4;
#pragma unroll
        for (int g = 0; g < 4; ++g) {
            const int ocol = n0 + wn * 64 + g * 16 + l15;
            const float bv = DIRECT ? bias[ocol] : 0.f;
#pragma unroll
            for (int r = 0; r < 4; ++r)
                dst[(size_t)(mrow + r) * N + ocol] = delta * acc[f][g][r] + bv;
        }
    }
}

// ---- combine: out = sum_y p_y + bias (fixed order -> deterministic) ----
__global__ __launch_bounds__(256) void combine(const float* __restrict__ p,
                                               const float* __restrict__ bias,
                                               float4* __restrict__ out)
{
    const int i4 = blockIdx.x * blockDim.x + threadIdx.x;
    constexpr int N4 = N / 4;                   // 2752
    if (i4 >= (int)(MN / 4)) return;
    const int col4 = i4 % N4;
    float4 s = *(const float4*)(bias + col4 * 4);
#pragma unroll
    for (int y = 0; y < KSPLIT; ++y) {
        float4 v = ((const float4*)(p + y * MN))[i4];
        s.x += v.x; s.y += v.y; s.z += v.z; s.w += v.w;
    }
    out[i4] = s;
}

extern "C" void kernel_launch(void* const* d_in, const int* in_sizes, int n_in,
                              void* d_out, int out_size, void* d_ws, size_t ws_size,
                              hipStream_t stream) {
    const float* x = (const float*)d_in[0];
    const float* w = (const float*)d_in[1];
    const float* bias = (const float*)d_in[2];
    float* out = (float*)d_out;
    float* partials = (float*)((char*)d_ws + PART_OFF);
    float* pbase = (float*)((char*)d_ws + P_OFF);

    if (ws_size >= WS_NEED_SPLIT) {
        const void* kf = reinterpret_cast<const void*>(&bitlinear_fused<true, false>);
        void* kargs[] = {(void*)&x, (void*)&w, (void*)&bias,
                         (void*)&partials, (void*)&pbase};
        hipError_t rc = hipLaunchCooperativeKernel(kf, dim3(NBX, KSPLIT), dim3(256),
                                                   kargs, 0, stream);
        if (rc != hipSuccess) {                 // coop unsupported -> 3-kernel path
            absmean_tiles<<<dim3(NBX, KSPLIT), 256, 0, stream>>>(w, partials);
            bitlinear_fused<false, false><<<dim3(NBX, KSPLIT), 256, 0, stream>>>(
                x, w, bias, partials, pbase);
        }
        combine<<<(int)(MN / 4 + 255) / 256, 256, 0, stream>>>(pbase, bias, (float4*)out);
    } else if (ws_size >= WS_NEED_MIN) {        // tiny ws: direct path
        absmean_tiles<<<dim3(NBX, KSPLIT), 256, 0, stream>>>(w, partials);
        bitlinear_fused<false, true><<<dim3(NBX, 1), 256, 0, stream>>>(
            x, w, bias, partials, out);
    }
}

// Round 11
// 71.666 us; speedup vs baseline: 1.9543x; 1.9543x over previous
//
#include <hip/hip_runtime.h>
#include <hip/hip_bf16.h>

typedef __bf16 bf16x8 __attribute__((ext_vector_type(8)));
typedef float f32x4 __attribute__((ext_vector_type(4)));
typedef unsigned short ushort8 __attribute__((ext_vector_type(8)));
typedef unsigned short ushort4v __attribute__((ext_vector_type(4)));

constexpr int M = 128;             // B*T
constexpr int K = 4096;            // IN
constexpr int N = 11008;           // OUT
constexpr int BN = 64;             // N cols per block
constexpr int BK = 32;             // K per step
constexpr int KSPLIT = 4;
constexpr int KBLK = K / KSPLIT;   // 1024
constexpr int NBX = N / BN;        // 172
constexpr long long NW = (long long)N * K;
constexpr int RBLK = 2048;
constexpr size_t MN = (size_t)M * N;

// ws layout
constexpr size_t PART_OFF = 0;                              // 2048 f32 partials
constexpr size_t XBF_OFF  = 8192;                           // X as bf16 (1 MB)
constexpr size_t P_OFF    = XBF_OFF + (size_t)M * K * 2;
constexpr size_t WS_NEED  = P_OFF + KSPLIT * MN * sizeof(float);
constexpr size_t WS_MIN   = RBLK * sizeof(float);

__device__ __forceinline__ unsigned short f2bf_bits(float f) {
    unsigned int u = __builtin_bit_cast(unsigned int, f);
    u += 0x7FFFu + ((u >> 16) & 1u);            // RNE to bf16
    return (unsigned short)(u >> 16);
}

// ---- pass 1: per-block partial |W| sums at FULL occupancy + X->bf16 ----
template <bool CVT>
__global__ __launch_bounds__(256) void absmean_partial(const float* __restrict__ w,
                                                       const float* __restrict__ x,
                                                       float* __restrict__ partials,
                                                       unsigned short* __restrict__ xbf)
{
    const int gtid = blockIdx.x * blockDim.x + threadIdx.x;
    if (CVT && gtid < M * K / 8) {
        const float4* xp = (const float4*)x + (size_t)gtid * 2;
        float4 a = xp[0], b = xp[1];
        ushort8 o;
        o[0] = f2bf_bits(a.x); o[1] = f2bf_bits(a.y);
        o[2] = f2bf_bits(a.z); o[3] = f2bf_bits(a.w);
        o[4] = f2bf_bits(b.x); o[5] = f2bf_bits(b.y);
        o[6] = f2bf_bits(b.z); o[7] = f2bf_bits(b.w);
        *(ushort8*)(xbf + (size_t)gtid * 8) = o;
    }
    const int n4 = (int)(NW / 4);
    const float4* w4 = (const float4*)w;
    float s0 = 0.f, s1 = 0.f, s2 = 0.f, s3 = 0.f;
    for (int i = gtid; i < n4; i += gridDim.x * blockDim.x) {
        float4 v = w4[i];
        s0 += fabsf(v.x); s1 += fabsf(v.y); s2 += fabsf(v.z); s3 += fabsf(v.w);
    }
    float s = (s0 + s1) + (s2 + s3);
#pragma unroll
    for (int off = 32; off > 0; off >>= 1) s += __shfl_down(s, off, 64);
    __shared__ float red[4];
    if ((threadIdx.x & 63) == 0) red[threadIdx.x >> 6] = s;
    __syncthreads();
    if (threadIdx.x == 0)
        partials[blockIdx.x] = (red[0] + red[1]) + (red[2] + red[3]);
}

// ---- pass 2: fused quantize + GEMM, latency-optimized ----
// BN=64/BK=32 -> 30.7 KB LDS -> 4 blocks/CU; 2-deep register prefetch.
// PRE:  grid(172,4), KSTEPS=32, X pre-cvt, partial out (no bias)
// !PRE: grid(172,1), KSTEPS=128, inline cvt, direct out + bias
template <int KSTEPS, bool PRE>
__global__ __launch_bounds__(256, 4) void bitlinear_gemm(
    const void* __restrict__ Xsrc, const float* __restrict__ W,
    const float* __restrict__ bias, const float* __restrict__ partials,
    float* __restrict__ dbase)
{
    constexpr int LDSW = 40;                    // 32 + 8 pad shorts (80 B rows)
    __shared__ __attribute__((aligned(16))) unsigned short xs[2][M * LDSW];   // 20.5 KB
    __shared__ __attribute__((aligned(16))) unsigned short wsm[2][BN * LDSW]; // 10.2 KB
    __shared__ float red[4];

    const int tid = threadIdx.x;
    const int lane = tid & 63;
    const int wid = tid >> 6;
    const int wm = wid >> 1;                    // 0..1: M 64-half
    const int wn = wid & 1;                     // 0..1: N 32-half
    const int cgrp = lane >> 4;                 // 0..3
    const int l15 = lane & 15;
    const int n0 = blockIdx.x * BN;
    const int kk0 = PRE ? blockIdx.y * KBLK : 0;
    const int K4 = K / 4;

    const unsigned short* xb = (const unsigned short*)Xsrc;
    const float4* x4p = (const float4*)Xsrc;
    const float4* w4p = (const float4*)W;

    // two register staging sets (named -> stays in registers, rule #20)
    ushort8 xrA[2], xrB[2];                     // X bf16 (PRE)
    float4 xfA[4], xfB[4];                      // X f32 (!PRE)
    float4 wrA[2], wrB[2];                      // W f32 (always exact)

    auto issue_set = [&](int t, ushort8 (&xr)[2], float4 (&xf)[4], float4 (&wr)[2]) {
        if constexpr (PRE) {
#pragma unroll
            for (int i = 0; i < 2; ++i) {       // 512 slots: row=j>>2, ch=j&3
                const int j = tid + i * 256;
                xr[i] = *(const ushort8*)(xb + (size_t)(j >> 2) * K + kk0 + t * BK + (j & 3) * 8);
            }
        } else {
#pragma unroll
            for (int i = 0; i < 4; ++i) {       // 1024 slots: row=j>>3, c4=j&7
                const int j = tid + i * 256;
                xf[i] = x4p[(size_t)(j >> 3) * K4 + (t * BK) / 4 + (j & 7)];
            }
        }
#pragma unroll
        for (int i = 0; i < 2; ++i) {           // 512 slots: row=j>>3, q=j&7
            const int j = tid + i * 256;
            wr[i] = w4p[(size_t)(n0 + (j >> 3)) * K4 + (kk0 + t * BK) / 4 + (j & 7)];
        }
    };

    // prologue: partials FIRST (their waitcnt won't drain tile loads),
    // then both prefetch depths in flight over the shuffle reduce.
    float ps[RBLK / 256];
#pragma unroll
    for (int i = 0; i < RBLK / 256; ++i) ps[i] = partials[tid + i * 256];

    issue_set(0, xrA, xfA, wrA);
    if (KSTEPS > 1) issue_set(1, xrB, xfB, wrB);

    float s = 0.f;
#pragma unroll
    for (int i = 0; i < RBLK / 256; ++i) s += ps[i];
#pragma unroll
    for (int off = 32; off > 0; off >>= 1) s += __shfl_down(s, off, 64);
    if (lane == 0) red[wid] = s;
    __syncthreads();
    const float delta =
        (float)((double)((red[0] + red[1]) + (red[2] + red[3])) / (double)NW + 1e-8);
    const float inv_delta = 1.0f / delta;

    auto stage_set = [&](int buf, ushort8 (&xr)[2], float4 (&xf)[4], float4 (&wr)[2]) {
        if constexpr (PRE) {
#pragma unroll
            for (int i = 0; i < 2; ++i) {
                const int j = tid + i * 256;
                *(ushort8*)&xs[buf][(j >> 2) * LDSW + (j & 3) * 8] = xr[i];
            }
        } else {
#pragma unroll
            for (int i = 0; i < 4; ++i) {
                const int j = tid + i * 256;
                float4 v = xf[i];
                ushort4v o;
                o[0] = f2bf_bits(v.x); o[1] = f2bf_bits(v.y);
                o[2] = f2bf_bits(v.z); o[3] = f2bf_bits(v.w);
                *(ushort4v*)&xs[buf][(j >> 3) * LDSW + (j & 7) * 4] = o;
            }
        }
#pragma unroll
        for (int i = 0; i < 2; ++i) {
            const int j = tid + i * 256;
            float wf[4] = {wr[i].x, wr[i].y, wr[i].z, wr[i].w};
            ushort4v wq;
#pragma unroll
            for (int e = 0; e < 4; ++e) {
                float qv = rintf(wf[e] * inv_delta);   // RNE = jnp.round, exact f32
                qv = fminf(1.f, fmaxf(-1.f, qv));
                wq[e] = f2bf_bits(qv);                 // exact bf16 {-1,0,+1}
            }
            *(ushort4v*)&wsm[buf][(j >> 3) * LDSW + (j & 7) * 4] = wq;
        }
    };

    f32x4 acc[4][2] = {};

    auto compute = [&](int buf) {
        const unsigned short* xcur = xs[buf];
        const unsigned short* wcur = wsm[buf];
        bf16x8 afr[4], bfr[2];
#pragma unroll
        for (int f = 0; f < 4; ++f)
            afr[f] = *(const bf16x8*)&xcur[(wm * 64 + f * 16 + l15) * LDSW + cgrp * 8];
#pragma unroll
        for (int g = 0; g < 2; ++g)
            bfr[g] = *(const bf16x8*)&wcur[(wn * 32 + g * 16 + l15) * LDSW + cgrp * 8];
#pragma unroll
        for (int f = 0; f < 4; ++f)
#pragma unroll
            for (int g = 0; g < 2; ++g)
                acc[f][g] = __builtin_amdgcn_mfma_f32_16x16x32_bf16(
                    afr[f], bfr[g], acc[f][g], 0, 0, 0);
    };

    // main loop: 2 tiles/iter, prefetch distance = 2 tiles
    for (int t = 0; t < KSTEPS; t += 2) {
        stage_set(0, xrA, xfA, wrA);            // tile t (loads issued at t-2)
        if (t + 2 < KSTEPS) issue_set(t + 2, xrA, xfA, wrA);
        __syncthreads();
        compute(0);
        stage_set(1, xrB, xfB, wrB);            // tile t+1
        if (t + 3 < KSTEPS) issue_set(t + 3, xrB, xfB, wrB);
        __syncthreads();
        compute(1);
    }

    // epilogue: D col=lane&15, row=(lane>>4)*4+reg (validated)
    float* dst = PRE ? dbase + (size_t)blockIdx.y * MN : dbase;
#pragma unroll
    for (int f = 0; f < 4; ++f) {
        const int mrow = wm * 64 + f * 16 + cgrp * 4;
#pragma unroll
        for (int g = 0; g < 2; ++g) {
            const int ocol = n0 + wn * 32 + g * 16 + l15;
            const float bv = PRE ? 0.f : bias[ocol];
#pragma unroll
            for (int r = 0; r < 4; ++r)
                dst[(size_t)(mrow + r) * N + ocol] = delta * acc[f][g][r] + bv;
        }
    }
}

// ---- pass 3: out = sum_y p_y + bias (fixed order -> deterministic) ----
__global__ __launch_bounds__(256) void combine(const float* __restrict__ p,
                                               const float* __restrict__ bias,
                                               float4* __restrict__ out)
{
    const int i4 = blockIdx.x * blockDim.x + threadIdx.x;
    constexpr int N4 = N / 4;                   // 2752
    if (i4 >= (int)(MN / 4)) return;
    const int col4 = i4 % N4;
    float4 s = *(const float4*)(bias + col4 * 4);
#pragma unroll
    for (int y = 0; y < KSPLIT; ++y) {
        float4 v = ((const float4*)(p + y * MN))[i4];
        s.x += v.x; s.y += v.y; s.z += v.z; s.w += v.w;
    }
    out[i4] = s;
}

extern "C" void kernel_launch(void* const* d_in, const int* in_sizes, int n_in,
                              void* d_out, int out_size, void* d_ws, size_t ws_size,
                              hipStream_t stream) {
    const float* x = (const float*)d_in[0];
    const float* w = (const float*)d_in[1];
    const float* bias = (const float*)d_in[2];
    float* out = (float*)d_out;
    float* partials = (float*)((char*)d_ws + PART_OFF);
    unsigned short* xbf = (unsigned short*)((char*)d_ws + XBF_OFF);
    float* pbase = (float*)((char*)d_ws + P_OFF);

    if (ws_size >= WS_NEED) {
        absmean_partial<true><<<RBLK, 256, 0, stream>>>(w, x, partials, xbf);
        bitlinear_gemm<KBLK / BK, true><<<dim3(NBX, KSPLIT), 256, 0, stream>>>(
            xbf, w, bias, partials, pbase);
        combine<<<(int)(MN / 4 + 255) / 256, 256, 0, stream>>>(pbase, bias, (float4*)out);
    } else if (ws_size >= WS_MIN) {
        absmean_partial<false><<<RBLK, 256, 0, stream>>>(w, x, partials, xbf);
        bitlinear_gemm<K / BK, false><<<dim3(NBX, 1), 256, 0, stream>>>(
            x, w, bias, partials, out);
    }
}